// Round 8
// baseline (243.811 us; speedup 1.0000x reference)
//
#include <hip/hip_runtime.h>
#include <cstdint>
#include <cstddef>

#define TT 8

#define E2_ELEMS (128*64*81)      // 663,552
#define E3_ELEMS (128*64*49)      // 401,408

typedef __attribute__((ext_vector_type(8))) short short8;
typedef __attribute__((ext_vector_type(4))) short short4v;
typedef __attribute__((ext_vector_type(4))) float f32x4;

// raw barrier: LDS-visibility only (no vmcnt drain -> global prefetches survive)
#define BAR_LDS() do { asm volatile("s_waitcnt lgkmcnt(0)" ::: "memory"); \
                       __builtin_amdgcn_s_barrier(); } while (0)

// async global->LDS, 16B per lane (dest must be lane-linear: base + lane*16)
__device__ __forceinline__ void gld_lds16(const void* g, void* l) {
  __builtin_amdgcn_global_load_lds((const __attribute__((address_space(1))) void*)g,
                                   (__attribute__((address_space(3))) void*)l, 16, 0, 0);
}

// exact 3-term bf16 split: v == h + m + l (each residual holds <= 8 mantissa bits)
__device__ __forceinline__ void split3(float v, ushort& h, ushort& m, ushort& l) {
  union { __bf16 b; ushort u; } H, M, L;
  H.b = (__bf16)v; float r1 = v - (float)H.b;
  M.b = (__bf16)r1; float r2 = r1 - (float)M.b;
  L.b = (__bf16)r2;
  h = H.u; m = M.u; l = L.u;
}

__device__ __forceinline__ short8 ld8(const ushort* p) {
  union { short4v h[2]; short8 v; } U;
  U.h[0] = *(const short4v*)(p);
  U.h[1] = *(const short4v*)(p + 4);
  return U.v;
}

// ---------------- merged weight preps: w1frag + w2frag + w3frag + wff ----------------
__global__ __launch_bounds__(256) void prep_all(const float* __restrict__ w1,
                                                const float* __restrict__ w2,
                                                const float* __restrict__ w3,
                                                const float* __restrict__ wfc,
                                                __bf16* __restrict__ w1f,
                                                __bf16* __restrict__ w2f,
                                                __bf16* __restrict__ w3f,
                                                __bf16* __restrict__ wff) {
  __shared__ float tile[12544];                     // 32 oc x 392 (8ci x 49pos)
  int bxx = blockIdx.x;
  int tid = threadIdx.x;

  if (bxx >= 912) {                                 // ---- fc1 weight prep path ----
    int bx2 = bxx - 912;
    int oc0 = (bx2 >> 3) * 32;
    int ci0 = (bx2 & 7) * 8;
    for (int f = tid; f < 12544; f += 256) {        // coalesced: 392-contig runs
      int oc_l = f / 392, r = f - oc_l * 392;
      tile[f] = wfc[(size_t)(oc0 + oc_l) * 3136 + ci0 * 49 + r];
    }
    __syncthreads();
    int squad = (ci0 & 31) >> 3;
    int sadd  = ci0 >> 5;
    for (int g = tid; g < 1568; g += 256) {         // 49 pos x 32 oc
      int pos = g >> 5, oc_l = g & 31;
      union { __bf16 h[8]; uint4 u; } T0, T1, T2;
      #pragma unroll
      for (int j = 0; j < 8; j++) {
        float wv = tile[oc_l * 392 + j * 49 + pos];
        float hf = (float)(__bf16)wv;
        float r1 = wv - hf;
        float mf = (float)(__bf16)r1;
        float r2 = r1 - mf;
        T0.h[j] = (__bf16)wv; T1.h[j] = (__bf16)r1; T2.h[j] = (__bf16)r2;
      }
      int s = pos * 2 + sadd;
      size_t b0 = (((size_t)s * 4 + squad) * 512 + oc0 + oc_l) * 8;
      *(uint4*)(wff + b0)           = T0.u;
      *(uint4*)(wff + b0 + 1605632) = T1.u;
      *(uint4*)(wff + b0 + 3211264) = T2.u;
    }
    return;
  }

  int i = bxx * 256 + tid;
  if (i < 98304) {                                  // conv2 frag, exact 3-term split
    int v = i;
    int j    = v & 7;
    int oc   = (v >> 3) & 63;
    int quad = (v >> 9) & 3;
    int ksg  = (v >> 11) & 15;
    int term = v >> 15;
    int k = ksg * 32 + quad * 8 + j;
    int ci = k >> 4, kpos = k & 15;
    float w = w2[oc * 512 + ci * 16 + kpos];
    float hf = (float)(__bf16)w;
    float r1 = w - hf;
    float mf = (float)(__bf16)r1;
    float r2 = r1 - mf;
    w2f[v] = (term == 0) ? (__bf16)w : (term == 1) ? (__bf16)r1 : (__bf16)r2;
  } else if (i < 208896) {                          // conv3 frag, pos-major K=576
    int v = i - 98304;
    int j    = v & 7;
    int oc   = (v >> 3) & 63;
    int quad = (v >> 9) & 3;
    int tk   = v >> 11;
    int term = tk / 18, kstep = tk % 18;
    int k = kstep * 32 + quad * 8 + j;
    int pos = k >> 6, ci = k & 63;
    float w = w3[oc * 576 + ci * 9 + pos];
    float hf = (float)(__bf16)w;
    float r1 = w - hf;
    float mf = (float)(__bf16)r1;
    float r2 = r1 - mf;
    w3f[v] = (term == 0) ? (__bf16)w : (term == 1) ? (__bf16)r1 : (__bf16)r2;
  } else {                                          // conv1 frag: [term][ks8][quad][oc32][8]
    int v = i - 208896;
    int j    = v & 7;
    int oc   = (v >> 3) & 31;
    int quad = (v >> 8) & 3;
    int ks   = (v >> 10) & 7;
    int term = v >> 13;
    int k = ks * 32 + quad * 8 + j;                 // k = ci*64 + ky*8 + kx
    float w = w1[oc * 256 + k];
    float hf = (float)(__bf16)w;
    float r1 = w - hf;
    float mf = (float)(__bf16)r1;
    float r2 = r1 - mf;
    w1f[v] = (term == 0) ? (__bf16)w : (term == 1) ? (__bf16)r1 : (__bf16)r2;
  }
}

// ---------------- conv1 via MFMA (3-term x * 3-term w, 8 of 9 products) ----------------
__global__ __launch_bounds__(128) void k_conv1m(const float* __restrict__ x,
                                                const __bf16* __restrict__ w1f,
                                                const float* __restrict__ bias,
                                                float* __restrict__ out,
                                                float* __restrict__ pout) {
  __shared__ ushort xs[24192];                      // 3 terms x 4 ci x 24 rows x 84 (48,384 B)
  int tid = threadIdx.x;
  int bx = blockIdx.x;
  int img = bx >> 2, q = bx & 3;
  const float* xb = x + (size_t)img * 28224 + q * 1680;
  for (int f = tid; f < 2016; f += 128) {
    int ci = f / 504, rr = f - ci * 504;
    int row = rr / 21, c4 = rr - row * 21;
    float4 v4 = *(const float4*)(xb + ci * 7056 + row * 84 + c4 * 4);
    union { ushort s[4]; uint2 u; } H, M, L;
    float vv[4] = {v4.x, v4.y, v4.z, v4.w};
    #pragma unroll
    for (int j = 0; j < 4; j++) split3(vv[j], H.s[j], M.s[j], L.s[j]);
    int eo = ci * 2016 + row * 84 + c4 * 4;
    *(uint2*)(xs + eo)         = H.u;
    *(uint2*)(xs + 8064 + eo)  = M.u;
    *(uint2*)(xs + 16128 + eo) = L.u;
  }
  __syncthreads();
  int nh = tid >> 6, lane = tid & 63;
  int l15 = lane & 15, quad = lane >> 4;
  int aoff[7];
  #pragma unroll
  for (int mt = 0; mt < 7; mt++) {
    int px = mt * 16 + l15; if (px > 99) px = 99;
    int oy = px / 20, ox = px - oy * 20;
    aoff[mt] = oy * 336 + ox * 4;
  }
  f32x4 acc[7];
  #pragma unroll
  for (int mt = 0; mt < 7; mt++) acc[mt] = (f32x4){0.f, 0.f, 0.f, 0.f};
  const __bf16* wpb = w1f + quad * 256 + (nh * 16 + l15) * 8;
  for (int ks = 0; ks < 8; ks++) {
    const __bf16* wp = wpb + ks * 1024;
    short8 bh = *(const short8*)(wp);
    short8 bm = *(const short8*)(wp + 8192);
    short8 bl = *(const short8*)(wp + 16384);
    int pair = ks * 4 + quad;
    int e0 = (pair >> 3) * 2016 + (pair & 7) * 84;
    short8 ah[7], am[7], al[7];
    #pragma unroll
    for (int mt = 0; mt < 7; mt++) {
      int e = e0 + aoff[mt];
      ah[mt] = ld8(xs + e);
      am[mt] = ld8(xs + 8064 + e);
      al[mt] = ld8(xs + 16128 + e);
    }
    #pragma unroll
    for (int mt = 0; mt < 7; mt++)
      acc[mt] = __builtin_amdgcn_mfma_f32_16x16x32_bf16(ah[mt], bh, acc[mt], 0, 0, 0);
    #pragma unroll
    for (int mt = 0; mt < 7; mt++)
      acc[mt] = __builtin_amdgcn_mfma_f32_16x16x32_bf16(ah[mt], bm, acc[mt], 0, 0, 0);
    #pragma unroll
    for (int mt = 0; mt < 7; mt++)
      acc[mt] = __builtin_amdgcn_mfma_f32_16x16x32_bf16(am[mt], bh, acc[mt], 0, 0, 0);
    #pragma unroll
    for (int mt = 0; mt < 7; mt++)
      acc[mt] = __builtin_amdgcn_mfma_f32_16x16x32_bf16(am[mt], bm, acc[mt], 0, 0, 0);
    #pragma unroll
    for (int mt = 0; mt < 7; mt++)
      acc[mt] = __builtin_amdgcn_mfma_f32_16x16x32_bf16(ah[mt], bl, acc[mt], 0, 0, 0);
    #pragma unroll
    for (int mt = 0; mt < 7; mt++)
      acc[mt] = __builtin_amdgcn_mfma_f32_16x16x32_bf16(al[mt], bh, acc[mt], 0, 0, 0);
    #pragma unroll
    for (int mt = 0; mt < 7; mt++)
      acc[mt] = __builtin_amdgcn_mfma_f32_16x16x32_bf16(am[mt], bl, acc[mt], 0, 0, 0);
    #pragma unroll
    for (int mt = 0; mt < 7; mt++)
      acc[mt] = __builtin_amdgcn_mfma_f32_16x16x32_bf16(al[mt], bm, acc[mt], 0, 0, 0);
  }
  int oc = nh * 16 + l15;
  float bv = bias[oc];
  float sl = 0.f, sl2 = 0.f;
  float* op = out + (size_t)img * 12800 + oc * 400 + q * 100;
  #pragma unroll
  for (int mt = 0; mt < 7; mt++) {
    int pxb = mt * 16 + quad * 4;
    #pragma unroll
    for (int r = 0; r < 4; r++) {
      int px = pxb + r;
      if (px < 100) {
        float v = acc[mt][r] + bv;
        op[px] = v;
        sl += v; sl2 += v * v;
      }
    }
  }
  __syncthreads();
  float* sred = (float*)xs;
  sred[oc * 4 + quad] = sl;
  sred[128 + oc * 4 + quad] = sl2;
  __syncthreads();
  if (tid < 32) {
    float s  = sred[tid*4] + sred[tid*4+1] + sred[tid*4+2] + sred[tid*4+3];
    float s2 = sred[128+tid*4] + sred[128+tid*4+1] + sred[128+tid*4+2] + sred[128+tid*4+3];
    pout[tid * 512 + bx] = s;
    pout[16384 + tid * 512 + bx] = s2;
  }
}

// ---------------- BN final: reduce 512 partials per channel ----------------
__global__ void k_bnfinal2(const float* __restrict__ pin, int sqoff, float n,
                           float* __restrict__ meanArr, float* __restrict__ rstdArr) {
  __shared__ float l0[256], l1[256];
  int c = blockIdx.x, tid = threadIdx.x;
  l0[tid] = pin[c * 512 + tid] + pin[c * 512 + tid + 256];
  l1[tid] = pin[sqoff + c * 512 + tid] + pin[sqoff + c * 512 + tid + 256];
  __syncthreads();
  for (int k = 128; k > 0; k >>= 1) {
    if (tid < k) { l0[tid] += l0[tid + k]; l1[tid] += l1[tid + k]; }
    __syncthreads();
  }
  if (tid == 0) {
    float m = l0[0] / n;
    float var = l1[0] / n - m * m;
    meanArr[c] = m;
    rstdArr[c] = rsqrtf(var + 1e-5f);
  }
}

// ---------------- BN + LIF stage 1 -> bit-packed spikes ----------------
__global__ void k_lif1b(const float* __restrict__ h, const float* __restrict__ mean,
                        const float* __restrict__ rstd, const float* __restrict__ g,
                        const float* __restrict__ bb, uint32_t* __restrict__ sout) {
  int idx = blockIdx.x * 256 + threadIdx.x;
  int ic = idx / 20;
  int ci = ic & 31;
  const float* hp = h + (size_t)idx * 20;
  float gm = g[ci], mm = mean[ci], rs = rstd[ci], bc = bb[ci];
  float xv[20];
  #pragma unroll
  for (int j4 = 0; j4 < 5; j4++) {
    float4 hv = ((const float4*)hp)[j4];
    xv[j4 * 4 + 0] = gm * (hv.x - mm) * rs + bc;
    xv[j4 * 4 + 1] = gm * (hv.y - mm) * rs + bc;
    xv[j4 * 4 + 2] = gm * (hv.z - mm) * rs + bc;
    xv[j4 * 4 + 3] = gm * (hv.w - mm) * rs + bc;
  }
  float v[20];
  #pragma unroll
  for (int j = 0; j < 20; j++) v[j] = 0.f;
  #pragma unroll
  for (int t = 0; t < TT; t++) {
    uint32_t w = 0;
    #pragma unroll
    for (int j = 0; j < 20; j++) {
      v[j] = v[j] + (xv[j] - v[j]) * 0.5f;
      uint32_t s = (v[j] >= 1.0f);
      w |= s << j;
      if (s) v[j] = 0.f;
    }
    sout[t * 81920 + idx] = w;
  }
}

// ---------------- conv2 via MFMA, weight-resident blocks ----------------
// v5: block = (4 imgs, 32-oc half). Stage 96KB weights + 10KB spikes ONCE;
// each wave computes one whole image, zero inner barriers. Bit-exact vs v2:
// MFMA order (ksg,term,nt,mt) and BN partial-sum order replicated.
__global__ __launch_bounds__(256) void k_conv2m(const uint32_t* __restrict__ s1b,
                                                const __bf16* __restrict__ wf,
                                                const float* __restrict__ bias,
                                                float* __restrict__ out,
                                                float* __restrict__ pout) {
  __shared__ uint4 wl4[6144];                       // 98,304 B: [192 chunks][256 bf16]
  __shared__ uint32_t sp[2560];                     // 4 imgs x 640
  __shared__ float sred[1024];
  __bf16* wl = (__bf16*)wl4;
  int tid = threadIdx.x;
  int bx = blockIdx.x;
  int img_group = bx >> 1;                          // 4 imgs per group
  int nh = bx & 1;                                  // oc half
  {
    const uint32_t* src = s1b + (size_t)img_group * 2560;
    for (int i = tid; i < 2560; i += 256) sp[i] = src[i];
  }
  // stage this half's weights: chunk c = ((ksg*3+term)*4+quad), 256 bf16 each
  #pragma unroll
  for (int r = 0; r < 24; r++) {
    int idx = r * 256 + tid;
    int chunk = idx >> 5, ln32 = idx & 31;
    int quad_c = chunk & 3, tq = chunk >> 2;
    int term = tq % 3, ksg = tq / 3;
    const __bf16* src = wf + term * 32768 + ksg * 2048 + quad_c * 512 + nh * 256 + ln32 * 8;
    gld_lds16(src, wl + idx * 8);
  }
  __syncthreads();                                  // the ONLY barrier before epilogue

  int wave = tid >> 6, lane = tid & 63;
  int img = img_group * 4 + wave;                   // wave owns one image
  int l15 = lane & 15, quad = lane >> 4;
  int ci_off = quad >> 1;
  int kyp = (quad & 1) * 2;
  int spb[6], sh[6];
  #pragma unroll
  for (int mt = 0; mt < 6; mt++) {
    int px = mt * 16 + l15;
    if (px > 80) px = 80;
    int oy = px / 9, ox = px - oy * 9;
    sh[mt]  = ox * 2;
    spb[mt] = wave * 640 + ci_off * 20 + oy * 2 + kyp;
  }
  f32x4 acc[6][2];
  #pragma unroll
  for (int mt = 0; mt < 6; mt++)
    #pragma unroll
    for (int nt = 0; nt < 2; nt++) acc[mt][nt] = (f32x4){0.f, 0.f, 0.f, 0.f};

  #pragma unroll 2
  for (int ksg = 0; ksg < 16; ksg++) {
    short8 a[6];
    #pragma unroll
    for (int mt = 0; mt < 6; mt++) {
      uint32_t w0 = sp[spb[mt] + ksg * 40];
      uint32_t w1 = sp[spb[mt] + ksg * 40 + 1];
      uint32_t n0 = (w0 >> sh[mt]) & 15u;
      uint32_t n1 = (w1 >> sh[mt]) & 15u;
      union { uint32_t u[4]; short8 v; } A;
      A.u[0] = ((n0 & 1u) ? 0x3F80u : 0u) | ((n0 & 2u) ? 0x3F800000u : 0u);
      A.u[1] = ((n0 & 4u) ? 0x3F80u : 0u) | ((n0 & 8u) ? 0x3F800000u : 0u);
      A.u[2] = ((n1 & 1u) ? 0x3F80u : 0u) | ((n1 & 2u) ? 0x3F800000u : 0u);
      A.u[3] = ((n1 & 4u) ? 0x3F80u : 0u) | ((n1 & 8u) ? 0x3F800000u : 0u);
      a[mt] = A.v;
    }
    #pragma unroll
    for (int term = 0; term < 3; term++) {
      #pragma unroll
      for (int nt = 0; nt < 2; nt++) {
        short8 b = *(const short8*)(wl + (((ksg * 3 + term) * 4 + quad) << 8) + (nt * 16 + l15) * 8);
        #pragma unroll
        for (int mt = 0; mt < 6; mt++)
          acc[mt][nt] = __builtin_amdgcn_mfma_f32_16x16x32_bf16(a[mt], b, acc[mt][nt], 0, 0, 0);
      }
    }
  }
  // ---- epilogue: out + BN partials (bit-exact replay of v2's order) ----
  float sl[2], sl2[2];
  #pragma unroll
  for (int nt = 0; nt < 2; nt++) {
    sl[nt] = 0.f; sl2[nt] = 0.f;
    int ocl = nt * 16 + l15;
    int oc = nh * 32 + ocl;
    float bv = bias[oc];
    float* op = out + ((size_t)img * 64 + oc) * 81;
    #pragma unroll
    for (int mt = 0; mt < 6; mt++) {
      int pxr = mt * 16 + quad * 4;
      #pragma unroll
      for (int r = 0; r < 4; r++) {
        int px = pxr + r;
        if (px < 81) {
          float v = acc[mt][nt][r] + bv;
          op[px] = v;
          sl[nt] += v; sl2[nt] += v * v;
        }
      }
    }
  }
  __syncthreads();                                  // done with sp-region? sred separate; sync for sred RW
  #pragma unroll
  for (int nt = 0; nt < 2; nt++) {
    int ocl = nt * 16 + l15;
    sred[ocl * 16 + wave * 4 + quad] = sl[nt];
    sred[512 + ocl * 16 + wave * 4 + quad] = sl2[nt];
  }
  __syncthreads();
  if (tid < 64) {
    int ocl = tid >> 1, bxl = tid & 1;              // old bx = img_group*2 + bxl
    float s = 0.f, s2 = 0.f;
    #pragma unroll
    for (int k = 0; k < 8; k++) {                   // k = old (img_local*4+quad) order
      s  += sred[ocl * 16 + bxl * 8 + k];
      s2 += sred[512 + ocl * 16 + bxl * 8 + k];
    }
    pout[(nh * 32 + ocl) * 512 + img_group * 2 + bxl] = s;
    pout[32768 + (nh * 32 + ocl) * 512 + img_group * 2 + bxl] = s2;
  }
}

// ---------------- fused stage-2 BN+LIF + transpose -> s2T (R3 version) ----------------
__global__ __launch_bounds__(256) void k_lifb2T(const float* __restrict__ h,
                                                const float* __restrict__ mean,
                                                const float* __restrict__ rstd,
                                                const float* __restrict__ g,
                                                const float* __restrict__ bb,
                                                uint32_t* __restrict__ s2T) {
  __shared__ uint32_t sb[288];
  int b = blockIdx.x, half = blockIdx.y;
  int tid = threadIdx.x;
  int c1 = half * 32 + tid / 9, py1 = tid % 9;
  bool has2 = tid < 32;
  int r2 = tid + 256;
  int c2i = half * 32 + r2 / 9, py2 = r2 % 9;
  float gm1 = g[c1], mm1 = mean[c1], rs1 = rstd[c1], bc1 = bb[c1];
  float gm2 = 0.f, mm2 = 0.f, rs2 = 0.f, bc2 = 0.f;
  if (has2) { gm2 = g[c2i]; mm2 = mean[c2i]; rs2 = rstd[c2i]; bc2 = bb[c2i]; }
  float v1[9], v2[9];
  #pragma unroll
  for (int j = 0; j < 9; j++) { v1[j] = 0.f; v2[j] = 0.f; }
  size_t base1 = ((size_t)b * 64 + c1) * 81 + py1 * 9;
  size_t base2 = has2 ? ((size_t)b * 64 + c2i) * 81 + py2 * 9 : base1;
  float c1v[9], c2v[9];
  {
    const float* hp = h;
    #pragma unroll
    for (int j = 0; j < 9; j++) c1v[j] = hp[base1 + j];
    if (has2) {
      #pragma unroll
      for (int j = 0; j < 9; j++) c2v[j] = hp[base2 + j];
    }
  }
  #pragma unroll 1
  for (int t = 0; t < TT; t++) {
    float n1v[9], n2v[9];
    if (t < TT - 1) {
      const float* hp = h + (size_t)(t + 1) * E2_ELEMS;
      #pragma unroll
      for (int j = 0; j < 9; j++) n1v[j] = hp[base1 + j];
      if (has2) {
        #pragma unroll
        for (int j = 0; j < 9; j++) n2v[j] = hp[base2 + j];
      }
    }
    uint32_t w = 0;
    #pragma unroll
    for (int j = 0; j < 9; j++) {
      float xv = gm1 * (c1v[j] - mm1) * rs1 + bc1;
      v1[j] = v1[j] + (xv - v1[j]) * 0.5f;
      uint32_t s = (v1[j] >= 1.0f);
      w |= s << j;
      if (s) v1[j] = 0.f;
    }
    sb[tid] = w;
    if (has2) {
      uint32_t w2 = 0;
      #pragma unroll
      for (int j = 0; j < 9; j++) {
        float xv = gm2 * (c2v[j] - mm2) * rs2 + bc2;
        v2[j] = v2[j] + (xv - v2[j]) * 0.5f;
        uint32_t s = (v2[j] >= 1.0f);
        w2 |= s << j;
        if (s) v2[j] = 0.f;
      }
      sb[r2] = w2;
    }
    BAR_LDS();
    if (tid < 81) {
      int r = tid / 9, cpix = tid - r * 9;
      uint32_t wo = 0;
      #pragma unroll
      for (int ci = 0; ci < 32; ci++)
        wo |= ((sb[ci * 9 + r] >> cpix) & 1u) << ci;
      s2T[(size_t)(t * 128 + b) * 162 + tid * 2 + half] = wo;
    }
    BAR_LDS();
    if (t < TT - 1) {
      #pragma unroll
      for (int j = 0; j < 9; j++) c1v[j] = n1v[j];
      if (has2) {
        #pragma unroll
        for (int j = 0; j < 9; j++) c2v[j] = n2v[j];
      }
    }
  }
}

// ---------------- conv3 via MFMA, weight-resident blocks ----------------
// v5: block = (4 imgs, 32-oc half), 108KB weights staged once, 1 barrier.
__global__ __launch_bounds__(256) void k_conv3m(const uint32_t* __restrict__ s2T,
                                                const __bf16* __restrict__ wf,
                                                const float* __restrict__ bias,
                                                float* __restrict__ out,
                                                float* __restrict__ pout) {
  __shared__ uint4 wl4[6912];                       // 110,592 B: [216 chunks][256 bf16]
  __shared__ uint32_t sp[648];                      // 4 imgs x 162
  __shared__ float sred[1024];
  __bf16* wl = (__bf16*)wl4;
  int tid = threadIdx.x;
  int bx = blockIdx.x;
  int img_group = bx >> 1;
  int nh = bx & 1;
  {
    const uint32_t* src = s2T + (size_t)img_group * 648;
    for (int i = tid; i < 648; i += 256) sp[i] = src[i];
  }
  // chunk c = ((kstep*3+term)*4+quad), 216 chunks, 27 rounds
  #pragma unroll
  for (int r = 0; r < 27; r++) {
    int idx = r * 256 + tid;
    int chunk = idx >> 5, ln32 = idx & 31;
    int quad_c = chunk & 3, tq = chunk >> 2;
    int term = tq % 3, kstep = tq / 3;
    const __bf16* src = wf + (term * 18 + kstep) * 2048 + quad_c * 512 + nh * 256 + ln32 * 8;
    gld_lds16(src, wl + idx * 8);
  }
  __syncthreads();

  int wave = tid >> 6, lane = tid & 63;
  int img = img_group * 4 + wave;
  int l15 = lane & 15, quad = lane >> 4;
  int qsh = quad * 8;
  int base[4];
  #pragma unroll
  for (int mt = 0; mt < 4; mt++) {
    int px = mt * 16 + l15;
    if (px > 48) px = 48;
    int oy = px / 7, ox = px - oy * 7;
    base[mt] = wave * 162 + (oy * 9 + ox) * 2;
  }
  f32x4 acc[4][2];
  #pragma unroll
  for (int mt = 0; mt < 4; mt++)
    #pragma unroll
    for (int nt = 0; nt < 2; nt++) acc[mt][nt] = (f32x4){0.f, 0.f, 0.f, 0.f};

  #pragma unroll 2
  for (int kstep = 0; kstep < 18; kstep++) {
    int pos = kstep >> 1, cihalf = kstep & 1;
    int ky = pos / 3, kx = pos % 3;
    short8 a[4];
    #pragma unroll
    for (int mt = 0; mt < 4; mt++) {
      uint32_t word = sp[base[mt] + (ky * 9 + kx) * 2 + cihalf];
      uint32_t byt = (word >> qsh) & 255u;
      union { uint32_t u[4]; short8 v; } A;
      A.u[0] = ((byt & 1u)  ? 0x3F80u : 0u) | ((byt & 2u)   ? 0x3F800000u : 0u);
      A.u[1] = ((byt & 4u)  ? 0x3F80u : 0u) | ((byt & 8u)   ? 0x3F800000u : 0u);
      A.u[2] = ((byt & 16u) ? 0x3F80u : 0u) | ((byt & 32u)  ? 0x3F800000u : 0u);
      A.u[3] = ((byt & 64u) ? 0x3F80u : 0u) | ((byt & 128u) ? 0x3F800000u : 0u);
      a[mt] = A.v;
    }
    #pragma unroll
    for (int term = 0; term < 3; term++) {
      #pragma unroll
      for (int nt = 0; nt < 2; nt++) {
        short8 b = *(const short8*)(wl + (((kstep * 3 + term) * 4 + quad) << 8) + (nt * 16 + l15) * 8);
        #pragma unroll
        for (int mt = 0; mt < 4; mt++)
          acc[mt][nt] = __builtin_amdgcn_mfma_f32_16x16x32_bf16(a[mt], b, acc[mt][nt], 0, 0, 0);
      }
    }
  }
  float sl[2], sl2[2];
  #pragma unroll
  for (int nt = 0; nt < 2; nt++) {
    sl[nt] = 0.f; sl2[nt] = 0.f;
    int ocl = nt * 16 + l15;
    int oc = nh * 32 + ocl;
    float bv = bias[oc];
    float* op = out + ((size_t)img * 64 + oc) * 49;
    #pragma unroll
    for (int mt = 0; mt < 4; mt++) {
      int pxr = mt * 16 + quad * 4;
      #pragma unroll
      for (int r = 0; r < 4; r++) {
        int px = pxr + r;
        if (px < 49) {
          float v = acc[mt][nt][r] + bv;
          op[px] = v;
          sl[nt] += v; sl2[nt] += v * v;
        }
      }
    }
  }
  __syncthreads();
  #pragma unroll
  for (int nt = 0; nt < 2; nt++) {
    int ocl = nt * 16 + l15;
    sred[ocl * 16 + wave * 4 + quad] = sl[nt];
    sred[512 + ocl * 16 + wave * 4 + quad] = sl2[nt];
  }
  __syncthreads();
  if (tid < 64) {
    int ocl = tid >> 1, bxl = tid & 1;
    float s = 0.f, s2 = 0.f;
    #pragma unroll
    for (int k = 0; k < 8; k++) {
      s  += sred[ocl * 16 + bxl * 8 + k];
      s2 += sred[512 + ocl * 16 + bxl * 8 + k];
    }
    pout[(nh * 32 + ocl) * 512 + img_group * 2 + bxl] = s;
    pout[32768 + (nh * 32 + ocl) * 512 + img_group * 2 + bxl] = s2;
  }
}

// ---------------- fused stage-3 BN+LIF + transpose -> s3T (R3 version) ----------------
__global__ __launch_bounds__(256) void k_lifb3T(const float* __restrict__ h,
                                                const float* __restrict__ mean,
                                                const float* __restrict__ rstd,
                                                const float* __restrict__ g,
                                                const float* __restrict__ bb,
                                                uint32_t* __restrict__ s3T) {
  __shared__ uint32_t sb[224];
  int b = blockIdx.x, half = blockIdx.y;
  int tid = threadIdx.x;
  bool active = tid < 224;
  int row = active ? tid : 0;
  int c = half * 32 + row / 7, py = row % 7;
  float gm = g[c], mm = mean[c], rs = rstd[c], bc = bb[c];
  float v[7];
  #pragma unroll
  for (int j = 0; j < 7; j++) v[j] = 0.f;
  size_t base = ((size_t)b * 64 + c) * 49 + py * 7;
  float cv[7];
  if (active) {
    #pragma unroll
    for (int j = 0; j < 7; j++) cv[j] = h[base + j];
  }
  #pragma unroll 1
  for (int t = 0; t < TT; t++) {
    float nv[7];
    if (active && t < TT - 1) {
      const float* hp = h + (size_t)(t + 1) * E3_ELEMS;
      #pragma unroll
      for (int j = 0; j < 7; j++) nv[j] = hp[base + j];
    }
    if (active) {
      uint32_t w = 0;
      #pragma unroll
      for (int j = 0; j < 7; j++) {
        float xv = gm * (cv[j] - mm) * rs + bc;
        v[j] = v[j] + (xv - v[j]) * 0.5f;
        uint32_t s = (v[j] >= 1.0f);
        w |= s << j;
        if (s) v[j] = 0.f;
      }
      sb[tid] = w;
    }
    BAR_LDS();
    if (tid < 49) {
      int py2 = tid / 7, px = tid - py2 * 7;
      uint32_t wo = 0;
      #pragma unroll
      for (int ci = 0; ci < 32; ci++)
        wo |= ((sb[ci * 7 + py2] >> px) & 1u) << ci;
      s3T[(size_t)(t * 128 + b) * 98 + tid * 2 + half] = wo;
    }
    BAR_LDS();
    if (active && t < TT - 1) {
      #pragma unroll
      for (int j = 0; j < 7; j++) cv[j] = nv[j];
    }
  }
}

// ---------------- fc1 via MFMA ----------------
__global__ __launch_bounds__(256) void k_fc1m(const uint32_t* __restrict__ s3T,
                                              const __bf16* __restrict__ wf,
                                              float* __restrict__ f1) {
  __shared__ uint32_t aS[6272];                     // 25,088 B; reused as red[] after loop
  int tid = threadIdx.x;
  int row0 = blockIdx.x * 64;
  int oc0  = blockIdx.y * 16;
  {
    const uint32_t* src = s3T + (size_t)row0 * 98;
    for (int i = tid; i < 6272; i += 256) aS[i] = src[i];
  }
  __syncthreads();
  int wave = tid >> 6, lane = tid & 63;
  int l15 = lane & 15, quad = lane >> 4;
  int qsh = quad * 8;
  f32x4 acc[4];
  #pragma unroll
  for (int mt = 0; mt < 4; mt++) acc[mt] = (f32x4){0.f, 0.f, 0.f, 0.f};
  int nIter = (wave < 2) ? 25 : 24;
  #pragma unroll 2
  for (int i = 0; i < nIter; i++) {
    int ks = i * 4 + wave;
    short8 a[4];
    #pragma unroll
    for (int mt = 0; mt < 4; mt++) {
      uint32_t word = aS[(mt * 16 + l15) * 98 + ks];
      uint32_t byt = (word >> qsh) & 255u;
      union { uint32_t u[4]; short8 v; } A;
      A.u[0] = ((byt & 1u)  ? 0x3F80u : 0u) | ((byt & 2u)   ? 0x3F800000u : 0u);
      A.u[1] = ((byt & 4u)  ? 0x3F80u : 0u) | ((byt & 8u)   ? 0x3F800000u : 0u);
      A.u[2] = ((byt & 16u) ? 0x3F80u : 0u) | ((byt & 32u)  ? 0x3F800000u : 0u);
      A.u[3] = ((byt & 64u) ? 0x3F80u : 0u) | ((byt & 128u) ? 0x3F800000u : 0u);
      a[mt] = A.v;
    }
    #pragma unroll
    for (int term = 0; term < 3; term++) {
      size_t fb = ((size_t)((term * 98 + ks) * 4 + quad) * 512 + oc0 + l15) * 8;
      short8 b = *(const short8*)(wf + fb);
      #pragma unroll
      for (int mt = 0; mt < 4; mt++)
        acc[mt] = __builtin_amdgcn_mfma_f32_16x16x32_bf16(a[mt], b, acc[mt], 0, 0, 0);
    }
  }
  __syncthreads();                                  // all aS reads done; reuse as red[]
  float* red = (float*)aS;                          // [4 waves][64 lanes][17] (pad=17)
  #pragma unroll
  for (int mt = 0; mt < 4; mt++)
    #pragma unroll
    for (int r = 0; r < 4; r++)
      red[(wave * 64 + lane) * 17 + mt * 4 + r] = acc[mt][r];
  __syncthreads();
  #pragma unroll
  for (int k = 0; k < 4; k++) {
    int oi = tid + k * 256;                         // 1024 outputs: 64 rows x 16 oc
    int row_l = oi >> 4, oc_l = oi & 15;
    int mt = row_l >> 4, rem = row_l & 15;
    int q2 = rem >> 2, r = rem & 3;
    int ln = q2 * 16 + oc_l;
    float s = red[(0 * 64 + ln) * 17 + mt * 4 + r]; // ordered: ((p0+p1)+p2)+p3
    s += red[(1 * 64 + ln) * 17 + mt * 4 + r];
    s += red[(2 * 64 + ln) * 17 + mt * 4 + r];
    s += red[(3 * 64 + ln) * 17 + mt * 4 + r];
    f1[(size_t)(row0 + row_l) * 512 + oc0 + oc_l] = s;
  }
}

// ---------------- fused: bias + LIF + fco + mean over T ----------
__global__ __launch_bounds__(256) void k_fc1fco(const float* __restrict__ f1,
                                                const float* __restrict__ bias,
                                                const float* __restrict__ w,
                                                const float* __restrict__ fcob,
                                                float* __restrict__ out) {
  int b = blockIdx.x, tid = threadIdx.x;
  int o0 = tid, o1 = tid + 256;
  float bv0 = bias[o0], bv1 = bias[o1];
  float w00 = w[o0], w10 = w[512 + o0];
  float w01 = w[o1], w11 = w[512 + o1];
  float x0[TT], x1[TT];
  #pragma unroll
  for (int t = 0; t < TT; t++) {
    x0[t] = f1[(size_t)(t * 128 + b) * 512 + o0];
    x1[t] = f1[(size_t)(t * 128 + b) * 512 + o1];
  }
  float v0 = 0.f, v1 = 0.f;
  float a0 = 0.f, a1 = 0.f;
  #pragma unroll
  for (int t = 0; t < TT; t++) {
    float s0 = x0[t] + bv0;
    v0 = v0 + (s0 - v0) * 0.5f;
    bool sp0 = (v0 >= 1.0f);
    if (sp0) v0 = 0.f;
    float s1 = x1[t] + bv1;
    v1 = v1 + (s1 - v1) * 0.5f;
    bool sp1 = (v1 >= 1.0f);
    if (sp1) v1 = 0.f;
    if (sp0) { a0 += w00; a1 += w10; }
    if (sp1) { a0 += w01; a1 += w11; }
  }
  __shared__ float l0[256], l1[256];
  l0[tid] = a0; l1[tid] = a1; __syncthreads();
  for (int k = 128; k > 0; k >>= 1) {
    if (tid < k) { l0[tid] += l0[tid + k]; l1[tid] += l1[tid + k]; }
    __syncthreads();
  }
  if (tid == 0) {
    out[b * 2 + 0] = l0[0] * 0.125f + fcob[0];
    out[b * 2 + 1] = l1[0] * 0.125f + fcob[1];
  }
}

extern "C" void kernel_launch(void* const* d_in, const int* in_sizes, int n_in,
                              void* d_out, int out_size, void* d_ws, size_t ws_size,
                              hipStream_t stream) {
  const float* x    = (const float*)d_in[0];
  const float* c1w  = (const float*)d_in[1];
  const float* c1b  = (const float*)d_in[2];
  const float* bn1g = (const float*)d_in[3];
  const float* bn1b = (const float*)d_in[4];
  const float* c2w  = (const float*)d_in[5];
  const float* c2b  = (const float*)d_in[6];
  const float* bn2g = (const float*)d_in[7];
  const float* bn2b = (const float*)d_in[8];
  const float* c3w  = (const float*)d_in[9];
  const float* c3b  = (const float*)d_in[10];
  const float* bn3g = (const float*)d_in[11];
  const float* bn3b = (const float*)d_in[12];
  const float* fc1w = (const float*)d_in[13];
  const float* fc1b = (const float*)d_in[14];
  const float* fcow = (const float*)d_in[15];
  const float* fcob = (const float*)d_in[16];
  float* out = (float*)d_out;

  char* ws = (char*)d_ws;
  float*    h1     = (float*)(ws + 0);                 //  6,553,600
  uint32_t* s1bits = (uint32_t*)(ws + 6553600);        //  2,621,440
  float*    h2     = (float*)(ws + 19660800);          // 21,233,664
  float*    h3     = (float*)(ws + 46202880);          // 12,845,056
  __bf16*   w2f    = (__bf16*)(ws + 60882944);         //    196,608
  __bf16*   w3f    = (__bf16*)(ws + 61079552);         //    221,184
  uint32_t* s2T    = (uint32_t*)(ws + 61300736);       //    663,552
  __bf16*   w1f    = (__bf16*)(ws + 62390272);         //     49,152
  float*    st     = (float*)(ws + 64880640);          //      320 floats
  __bf16*   wff    = (__bf16*)(ws + 67108864);         //  9,633,792
  float*    f1sum  = (float*)(ws + 76742656);          //  2,097,152
  uint32_t* s3T    = (uint32_t*)(ws + 85131264);       //    401,408
  float*    bnpart = (float*)(ws + 85532672);          //    262,144

  prep_all   <<<1040, 256, 0, stream>>>(c1w, c2w, c3w, fc1w, w1f, w2f, w3f, wff);

  k_conv1m   <<<512, 128, 0, stream>>>(x, w1f, c1b, h1, bnpart);
  k_bnfinal2 <<<32, 256, 0, stream>>>(bnpart, 16384, 51200.f, st, st + 32);
  k_lif1b    <<<320, 256, 0, stream>>>(h1, st, st + 32, bn1g, bn1b, s1bits);

  k_conv2m   <<<512, 256, 0, stream>>>(s1bits, w2f, c2b, h2, bnpart);
  k_bnfinal2 <<<64, 256, 0, stream>>>(bnpart, 32768, 82944.f, st + 64, st + 128);
  k_lifb2T   <<<dim3(128, 2), 256, 0, stream>>>(h2, st + 64, st + 128, bn2g, bn2b, s2T);

  k_conv3m   <<<512, 256, 0, stream>>>(s2T, w3f, c3b, h3, bnpart);
  k_bnfinal2 <<<64, 256, 0, stream>>>(bnpart, 32768, 50176.f, st + 192, st + 256);
  k_lifb3T   <<<dim3(128, 2), 256, 0, stream>>>(h3, st + 192, st + 256, bn3g, bn3b, s3T);

  k_fc1m     <<<dim3(16, 32), 256, 0, stream>>>(s3T, wff, f1sum);
  k_fc1fco   <<<128, 256, 0, stream>>>(f1sum, fc1b, fcow, fcob, out);
}

// Round 9
// 232.689 us; speedup vs baseline: 1.0478x; 1.0478x over previous
//
#include <hip/hip_runtime.h>
#include <cstdint>
#include <cstddef>

#define TT 8

#define E2_ELEMS (128*64*81)      // 663,552
#define E3_ELEMS (128*64*49)      // 401,408

typedef __attribute__((ext_vector_type(8))) short short8;
typedef __attribute__((ext_vector_type(4))) short short4v;
typedef __attribute__((ext_vector_type(4))) float f32x4;

// raw barrier: LDS-visibility only (no vmcnt drain -> global prefetches survive)
#define BAR_LDS() do { asm volatile("s_waitcnt lgkmcnt(0)" ::: "memory"); \
                       __builtin_amdgcn_s_barrier(); } while (0)

// async global->LDS, 16B per lane (dest must be lane-linear: base + lane*16)
__device__ __forceinline__ void gld_lds16(const void* g, void* l) {
  __builtin_amdgcn_global_load_lds((const __attribute__((address_space(1))) void*)g,
                                   (__attribute__((address_space(3))) void*)l, 16, 0, 0);
}

// exact 3-term bf16 split: v == h + m + l (each residual holds <= 8 mantissa bits)
__device__ __forceinline__ void split3(float v, ushort& h, ushort& m, ushort& l) {
  union { __bf16 b; ushort u; } H, M, L;
  H.b = (__bf16)v; float r1 = v - (float)H.b;
  M.b = (__bf16)r1; float r2 = r1 - (float)M.b;
  L.b = (__bf16)r2;
  h = H.u; m = M.u; l = L.u;
}

__device__ __forceinline__ short8 ld8(const ushort* p) {
  union { short4v h[2]; short8 v; } U;
  U.h[0] = *(const short4v*)(p);
  U.h[1] = *(const short4v*)(p + 4);
  return U.v;
}

// ---------------- merged weight preps: w1frag + w2frag + w3frag + wff ----------------
__global__ __launch_bounds__(256) void prep_all(const float* __restrict__ w1,
                                                const float* __restrict__ w2,
                                                const float* __restrict__ w3,
                                                const float* __restrict__ wfc,
                                                __bf16* __restrict__ w1f,
                                                __bf16* __restrict__ w2f,
                                                __bf16* __restrict__ w3f,
                                                __bf16* __restrict__ wff) {
  __shared__ float tile[12544];                     // 32 oc x 392 (8ci x 49pos)
  int bxx = blockIdx.x;
  int tid = threadIdx.x;

  if (bxx >= 912) {                                 // ---- fc1 weight prep path ----
    int bx2 = bxx - 912;
    int oc0 = (bx2 >> 3) * 32;
    int ci0 = (bx2 & 7) * 8;
    for (int f = tid; f < 12544; f += 256) {        // coalesced: 392-contig runs
      int oc_l = f / 392, r = f - oc_l * 392;
      tile[f] = wfc[(size_t)(oc0 + oc_l) * 3136 + ci0 * 49 + r];
    }
    __syncthreads();
    int squad = (ci0 & 31) >> 3;
    int sadd  = ci0 >> 5;
    for (int g = tid; g < 1568; g += 256) {         // 49 pos x 32 oc
      int pos = g >> 5, oc_l = g & 31;
      union { __bf16 h[8]; uint4 u; } T0, T1, T2;
      #pragma unroll
      for (int j = 0; j < 8; j++) {
        float wv = tile[oc_l * 392 + j * 49 + pos];
        float hf = (float)(__bf16)wv;
        float r1 = wv - hf;
        float mf = (float)(__bf16)r1;
        float r2 = r1 - mf;
        T0.h[j] = (__bf16)wv; T1.h[j] = (__bf16)r1; T2.h[j] = (__bf16)r2;
      }
      int s = pos * 2 + sadd;
      size_t b0 = (((size_t)s * 4 + squad) * 512 + oc0 + oc_l) * 8;
      *(uint4*)(wff + b0)           = T0.u;
      *(uint4*)(wff + b0 + 1605632) = T1.u;
      *(uint4*)(wff + b0 + 3211264) = T2.u;
    }
    return;
  }

  int i = bxx * 256 + tid;
  if (i < 98304) {                                  // conv2 frag, exact 3-term split
    int v = i;
    int j    = v & 7;
    int oc   = (v >> 3) & 63;
    int quad = (v >> 9) & 3;
    int ksg  = (v >> 11) & 15;
    int term = v >> 15;
    int k = ksg * 32 + quad * 8 + j;
    int ci = k >> 4, kpos = k & 15;
    float w = w2[oc * 512 + ci * 16 + kpos];
    float hf = (float)(__bf16)w;
    float r1 = w - hf;
    float mf = (float)(__bf16)r1;
    float r2 = r1 - mf;
    w2f[v] = (term == 0) ? (__bf16)w : (term == 1) ? (__bf16)r1 : (__bf16)r2;
  } else if (i < 208896) {                          // conv3 frag, pos-major K=576
    int v = i - 98304;
    int j    = v & 7;
    int oc   = (v >> 3) & 63;
    int quad = (v >> 9) & 3;
    int tk   = v >> 11;
    int term = tk / 18, kstep = tk % 18;
    int k = kstep * 32 + quad * 8 + j;
    int pos = k >> 6, ci = k & 63;
    float w = w3[oc * 576 + ci * 9 + pos];
    float hf = (float)(__bf16)w;
    float r1 = w - hf;
    float mf = (float)(__bf16)r1;
    float r2 = r1 - mf;
    w3f[v] = (term == 0) ? (__bf16)w : (term == 1) ? (__bf16)r1 : (__bf16)r2;
  } else {                                          // conv1 frag: [term][ks8][quad][oc32][8]
    int v = i - 208896;
    int j    = v & 7;
    int oc   = (v >> 3) & 31;
    int quad = (v >> 8) & 3;
    int ks   = (v >> 10) & 7;
    int term = v >> 13;
    int k = ks * 32 + quad * 8 + j;                 // k = ci*64 + ky*8 + kx
    float w = w1[oc * 256 + k];
    float hf = (float)(__bf16)w;
    float r1 = w - hf;
    float mf = (float)(__bf16)r1;
    float r2 = r1 - mf;
    w1f[v] = (term == 0) ? (__bf16)w : (term == 1) ? (__bf16)r1 : (__bf16)r2;
  }
}

// ---------------- conv1 via MFMA (3-term x * 3-term w, 8 of 9 products) ----------------
__global__ __launch_bounds__(128) void k_conv1m(const float* __restrict__ x,
                                                const __bf16* __restrict__ w1f,
                                                const float* __restrict__ bias,
                                                float* __restrict__ out,
                                                float* __restrict__ pout) {
  __shared__ ushort xs[24192];                      // 3 terms x 4 ci x 24 rows x 84 (48,384 B)
  int tid = threadIdx.x;
  int bx = blockIdx.x;
  int img = bx >> 2, q = bx & 3;
  const float* xb = x + (size_t)img * 28224 + q * 1680;
  for (int f = tid; f < 2016; f += 128) {
    int ci = f / 504, rr = f - ci * 504;
    int row = rr / 21, c4 = rr - row * 21;
    float4 v4 = *(const float4*)(xb + ci * 7056 + row * 84 + c4 * 4);
    union { ushort s[4]; uint2 u; } H, M, L;
    float vv[4] = {v4.x, v4.y, v4.z, v4.w};
    #pragma unroll
    for (int j = 0; j < 4; j++) split3(vv[j], H.s[j], M.s[j], L.s[j]);
    int eo = ci * 2016 + row * 84 + c4 * 4;
    *(uint2*)(xs + eo)         = H.u;
    *(uint2*)(xs + 8064 + eo)  = M.u;
    *(uint2*)(xs + 16128 + eo) = L.u;
  }
  __syncthreads();
  int nh = tid >> 6, lane = tid & 63;
  int l15 = lane & 15, quad = lane >> 4;
  int aoff[7];
  #pragma unroll
  for (int mt = 0; mt < 7; mt++) {
    int px = mt * 16 + l15; if (px > 99) px = 99;
    int oy = px / 20, ox = px - oy * 20;
    aoff[mt] = oy * 336 + ox * 4;
  }
  f32x4 acc[7];
  #pragma unroll
  for (int mt = 0; mt < 7; mt++) acc[mt] = (f32x4){0.f, 0.f, 0.f, 0.f};
  const __bf16* wpb = w1f + quad * 256 + (nh * 16 + l15) * 8;
  for (int ks = 0; ks < 8; ks++) {
    const __bf16* wp = wpb + ks * 1024;
    short8 bh = *(const short8*)(wp);
    short8 bm = *(const short8*)(wp + 8192);
    short8 bl = *(const short8*)(wp + 16384);
    int pair = ks * 4 + quad;
    int e0 = (pair >> 3) * 2016 + (pair & 7) * 84;
    short8 ah[7], am[7], al[7];
    #pragma unroll
    for (int mt = 0; mt < 7; mt++) {
      int e = e0 + aoff[mt];
      ah[mt] = ld8(xs + e);
      am[mt] = ld8(xs + 8064 + e);
      al[mt] = ld8(xs + 16128 + e);
    }
    #pragma unroll
    for (int mt = 0; mt < 7; mt++)
      acc[mt] = __builtin_amdgcn_mfma_f32_16x16x32_bf16(ah[mt], bh, acc[mt], 0, 0, 0);
    #pragma unroll
    for (int mt = 0; mt < 7; mt++)
      acc[mt] = __builtin_amdgcn_mfma_f32_16x16x32_bf16(ah[mt], bm, acc[mt], 0, 0, 0);
    #pragma unroll
    for (int mt = 0; mt < 7; mt++)
      acc[mt] = __builtin_amdgcn_mfma_f32_16x16x32_bf16(am[mt], bh, acc[mt], 0, 0, 0);
    #pragma unroll
    for (int mt = 0; mt < 7; mt++)
      acc[mt] = __builtin_amdgcn_mfma_f32_16x16x32_bf16(am[mt], bm, acc[mt], 0, 0, 0);
    #pragma unroll
    for (int mt = 0; mt < 7; mt++)
      acc[mt] = __builtin_amdgcn_mfma_f32_16x16x32_bf16(ah[mt], bl, acc[mt], 0, 0, 0);
    #pragma unroll
    for (int mt = 0; mt < 7; mt++)
      acc[mt] = __builtin_amdgcn_mfma_f32_16x16x32_bf16(al[mt], bh, acc[mt], 0, 0, 0);
    #pragma unroll
    for (int mt = 0; mt < 7; mt++)
      acc[mt] = __builtin_amdgcn_mfma_f32_16x16x32_bf16(am[mt], bl, acc[mt], 0, 0, 0);
    #pragma unroll
    for (int mt = 0; mt < 7; mt++)
      acc[mt] = __builtin_amdgcn_mfma_f32_16x16x32_bf16(al[mt], bm, acc[mt], 0, 0, 0);
  }
  int oc = nh * 16 + l15;
  float bv = bias[oc];
  float sl = 0.f, sl2 = 0.f;
  float* op = out + (size_t)img * 12800 + oc * 400 + q * 100;
  #pragma unroll
  for (int mt = 0; mt < 7; mt++) {
    int pxb = mt * 16 + quad * 4;
    #pragma unroll
    for (int r = 0; r < 4; r++) {
      int px = pxb + r;
      if (px < 100) {
        float v = acc[mt][r] + bv;
        op[px] = v;
        sl += v; sl2 += v * v;
      }
    }
  }
  __syncthreads();
  float* sred = (float*)xs;
  sred[oc * 4 + quad] = sl;
  sred[128 + oc * 4 + quad] = sl2;
  __syncthreads();
  if (tid < 32) {
    float s  = sred[tid*4] + sred[tid*4+1] + sred[tid*4+2] + sred[tid*4+3];
    float s2 = sred[128+tid*4] + sred[128+tid*4+1] + sred[128+tid*4+2] + sred[128+tid*4+3];
    pout[tid * 512 + bx] = s;
    pout[16384 + tid * 512 + bx] = s2;
  }
}

// ---------------- BN final: reduce 512 partials per channel ----------------
__global__ void k_bnfinal2(const float* __restrict__ pin, int sqoff, float n,
                           float* __restrict__ meanArr, float* __restrict__ rstdArr) {
  __shared__ float l0[256], l1[256];
  int c = blockIdx.x, tid = threadIdx.x;
  l0[tid] = pin[c * 512 + tid] + pin[c * 512 + tid + 256];
  l1[tid] = pin[sqoff + c * 512 + tid] + pin[sqoff + c * 512 + tid + 256];
  __syncthreads();
  for (int k = 128; k > 0; k >>= 1) {
    if (tid < k) { l0[tid] += l0[tid + k]; l1[tid] += l1[tid + k]; }
    __syncthreads();
  }
  if (tid == 0) {
    float m = l0[0] / n;
    float var = l1[0] / n - m * m;
    meanArr[c] = m;
    rstdArr[c] = rsqrtf(var + 1e-5f);
  }
}

// ---------------- BN + LIF stage 1 -> bit-packed spikes ----------------
__global__ void k_lif1b(const float* __restrict__ h, const float* __restrict__ mean,
                        const float* __restrict__ rstd, const float* __restrict__ g,
                        const float* __restrict__ bb, uint32_t* __restrict__ sout) {
  int idx = blockIdx.x * 256 + threadIdx.x;
  int ic = idx / 20;
  int ci = ic & 31;
  const float* hp = h + (size_t)idx * 20;
  float gm = g[ci], mm = mean[ci], rs = rstd[ci], bc = bb[ci];
  float xv[20];
  #pragma unroll
  for (int j4 = 0; j4 < 5; j4++) {
    float4 hv = ((const float4*)hp)[j4];
    xv[j4 * 4 + 0] = gm * (hv.x - mm) * rs + bc;
    xv[j4 * 4 + 1] = gm * (hv.y - mm) * rs + bc;
    xv[j4 * 4 + 2] = gm * (hv.z - mm) * rs + bc;
    xv[j4 * 4 + 3] = gm * (hv.w - mm) * rs + bc;
  }
  float v[20];
  #pragma unroll
  for (int j = 0; j < 20; j++) v[j] = 0.f;
  #pragma unroll
  for (int t = 0; t < TT; t++) {
    uint32_t w = 0;
    #pragma unroll
    for (int j = 0; j < 20; j++) {
      v[j] = v[j] + (xv[j] - v[j]) * 0.5f;
      uint32_t s = (v[j] >= 1.0f);
      w |= s << j;
      if (s) v[j] = 0.f;
    }
    sout[t * 81920 + idx] = w;
  }
}

// ---------------- conv2 via MFMA + fused BN partial stats ----------------
__global__ __launch_bounds__(256) void k_conv2m(const uint32_t* __restrict__ s1b,
                                                const __bf16* __restrict__ wf,
                                                const float* __restrict__ bias,
                                                float* __restrict__ out,
                                                float* __restrict__ pout) {
  __shared__ uint32_t sp[1280];
  __shared__ uint4 wl4[3072];                       // 49,152 B (reused for stats)
  __bf16* wl = (__bf16*)wl4;
  int tid = threadIdx.x;
  int img0 = blockIdx.x * 2;
  {
    const uint32_t* src = s1b + (size_t)img0 * 640;
    for (int i = tid; i < 1280; i += 256) sp[i] = src[i];
  }
  int wave = tid >> 6, lane = tid & 63;
  int img_local = wave >> 1;
  int nh = wave & 1;
  int l15 = lane & 15, quad = lane >> 4;
  int ci_off = quad >> 1;
  int kyp = (quad & 1) * 2;
  int spb[6], sh[6];
  #pragma unroll
  for (int mt = 0; mt < 6; mt++) {
    int px = mt * 16 + l15;
    if (px > 80) px = 80;
    int oy = px / 9, ox = px - oy * 9;
    sh[mt]  = ox * 2;
    spb[mt] = img_local * 640 + ci_off * 20 + oy * 2 + kyp;
  }
  f32x4 acc[6][2];
  #pragma unroll
  for (int mt = 0; mt < 6; mt++)
    #pragma unroll
    for (int nt = 0; nt < 2; nt++) acc[mt][nt] = (f32x4){0.f, 0.f, 0.f, 0.f};

  for (int kc = 0; kc < 4; kc++) {
    __syncthreads();
    for (int o = tid * 8; o < 24576; o += 2048) {   // async 16B/lane global->LDS
      int tk = o >> 11;
      int term = tk >> 2, ksl = tk & 3;
      const __bf16* src = wf + (((term * 16 + kc * 4 + ksl)) << 11) + (o & 2047);
      gld_lds16(src, wl + o);
    }
    __syncthreads();
    #pragma unroll
    for (int ks = 0; ks < 4; ks++) {
      int ksg = kc * 4 + ks;
      short8 a[6];
      #pragma unroll
      for (int mt = 0; mt < 6; mt++) {
        uint32_t w0 = sp[spb[mt] + ksg * 40];
        uint32_t w1 = sp[spb[mt] + ksg * 40 + 1];
        uint32_t n0 = (w0 >> sh[mt]) & 15u;
        uint32_t n1 = (w1 >> sh[mt]) & 15u;
        union { uint32_t u[4]; short8 v; } A;
        A.u[0] = ((n0 & 1u) ? 0x3F80u : 0u) | ((n0 & 2u) ? 0x3F800000u : 0u);
        A.u[1] = ((n0 & 4u) ? 0x3F80u : 0u) | ((n0 & 8u) ? 0x3F800000u : 0u);
        A.u[2] = ((n1 & 1u) ? 0x3F80u : 0u) | ((n1 & 2u) ? 0x3F800000u : 0u);
        A.u[3] = ((n1 & 4u) ? 0x3F80u : 0u) | ((n1 & 8u) ? 0x3F800000u : 0u);
        a[mt] = A.v;
      }
      #pragma unroll
      for (int term = 0; term < 3; term++) {
        int fb = ((term * 4 + ks) << 11) + (quad << 9);
        #pragma unroll
        for (int nt = 0; nt < 2; nt++) {
          short8 b = *(const short8*)(wl + fb + ((((nh << 1) | nt) << 4) + l15) * 8);
          #pragma unroll
          for (int mt = 0; mt < 6; mt++)
            acc[mt][nt] = __builtin_amdgcn_mfma_f32_16x16x32_bf16(a[mt], b, acc[mt][nt], 0, 0, 0);
        }
      }
    }
  }
  float sl[2], sl2[2];
  #pragma unroll
  for (int nt = 0; nt < 2; nt++) {
    sl[nt] = 0.f; sl2[nt] = 0.f;
    int oc = nh * 32 + nt * 16 + l15;
    float bv = bias[oc];
    float* op = out + ((size_t)(img0 + img_local) * 64 + oc) * 81;
    #pragma unroll
    for (int mt = 0; mt < 6; mt++) {
      int pxr = mt * 16 + quad * 4;
      #pragma unroll
      for (int r = 0; r < 4; r++) {
        int px = pxr + r;
        if (px < 81) {
          float v = acc[mt][nt][r] + bv;
          op[px] = v;
          sl[nt] += v; sl2[nt] += v * v;
        }
      }
    }
  }
  __syncthreads();
  float* sred = (float*)wl4;                        // [64oc][8] + [64oc][8]
  #pragma unroll
  for (int nt = 0; nt < 2; nt++) {
    int oc = nh * 32 + nt * 16 + l15;
    int idx = oc * 8 + img_local * 4 + quad;
    sred[idx] = sl[nt];
    sred[512 + idx] = sl2[nt];
  }
  __syncthreads();
  if (tid < 64) {
    float s = 0.f, s2 = 0.f;
    #pragma unroll
    for (int k = 0; k < 8; k++) { s += sred[tid * 8 + k]; s2 += sred[512 + tid * 8 + k]; }
    pout[tid * 512 + blockIdx.x] = s;
    pout[32768 + tid * 512 + blockIdx.x] = s2;
  }
}

// ---------------- fused stage-2 BN+LIF + transpose -> s2T ----------------
__global__ __launch_bounds__(256) void k_lifb2T(const float* __restrict__ h,
                                                const float* __restrict__ mean,
                                                const float* __restrict__ rstd,
                                                const float* __restrict__ g,
                                                const float* __restrict__ bb,
                                                uint32_t* __restrict__ s2T) {
  __shared__ uint32_t sb[288];
  int b = blockIdx.x, half = blockIdx.y;
  int tid = threadIdx.x;
  int c1 = half * 32 + tid / 9, py1 = tid % 9;
  bool has2 = tid < 32;
  int r2 = tid + 256;
  int c2i = half * 32 + r2 / 9, py2 = r2 % 9;
  float gm1 = g[c1], mm1 = mean[c1], rs1 = rstd[c1], bc1 = bb[c1];
  float gm2 = 0.f, mm2 = 0.f, rs2 = 0.f, bc2 = 0.f;
  if (has2) { gm2 = g[c2i]; mm2 = mean[c2i]; rs2 = rstd[c2i]; bc2 = bb[c2i]; }
  float v1[9], v2[9];
  #pragma unroll
  for (int j = 0; j < 9; j++) { v1[j] = 0.f; v2[j] = 0.f; }
  size_t base1 = ((size_t)b * 64 + c1) * 81 + py1 * 9;
  size_t base2 = has2 ? ((size_t)b * 64 + c2i) * 81 + py2 * 9 : base1;
  float c1v[9], c2v[9];
  {
    const float* hp = h;
    #pragma unroll
    for (int j = 0; j < 9; j++) c1v[j] = hp[base1 + j];
    if (has2) {
      #pragma unroll
      for (int j = 0; j < 9; j++) c2v[j] = hp[base2 + j];
    }
  }
  #pragma unroll 1
  for (int t = 0; t < TT; t++) {
    float n1v[9], n2v[9];
    if (t < TT - 1) {                               // prefetch t+1 early
      const float* hp = h + (size_t)(t + 1) * E2_ELEMS;
      #pragma unroll
      for (int j = 0; j < 9; j++) n1v[j] = hp[base1 + j];
      if (has2) {
        #pragma unroll
        for (int j = 0; j < 9; j++) n2v[j] = hp[base2 + j];
      }
    }
    uint32_t w = 0;
    #pragma unroll
    for (int j = 0; j < 9; j++) {
      float xv = gm1 * (c1v[j] - mm1) * rs1 + bc1;
      v1[j] = v1[j] + (xv - v1[j]) * 0.5f;
      uint32_t s = (v1[j] >= 1.0f);
      w |= s << j;
      if (s) v1[j] = 0.f;
    }
    sb[tid] = w;
    if (has2) {
      uint32_t w2 = 0;
      #pragma unroll
      for (int j = 0; j < 9; j++) {
        float xv = gm2 * (c2v[j] - mm2) * rs2 + bc2;
        v2[j] = v2[j] + (xv - v2[j]) * 0.5f;
        uint32_t s = (v2[j] >= 1.0f);
        w2 |= s << j;
        if (s) v2[j] = 0.f;
      }
      sb[r2] = w2;
    }
    BAR_LDS();
    if (tid < 81) {
      int r = tid / 9, cpix = tid - r * 9;
      uint32_t wo = 0;
      #pragma unroll
      for (int ci = 0; ci < 32; ci++)
        wo |= ((sb[ci * 9 + r] >> cpix) & 1u) << ci;
      s2T[(size_t)(t * 128 + b) * 162 + tid * 2 + half] = wo;
    }
    BAR_LDS();
    if (t < TT - 1) {
      #pragma unroll
      for (int j = 0; j < 9; j++) c1v[j] = n1v[j];
      if (has2) {
        #pragma unroll
        for (int j = 0; j < 9; j++) c2v[j] = n2v[j];
      }
    }
  }
}

// ---------------- conv3 via MFMA + fused BN partial stats ----------------
__global__ __launch_bounds__(256) void k_conv3m(const uint32_t* __restrict__ s2T,
                                                const __bf16* __restrict__ wf,
                                                const float* __restrict__ bias,
                                                float* __restrict__ out,
                                                float* __restrict__ pout) {
  __shared__ uint32_t sp[324];
  __shared__ uint4 wl4[4608];                       // 73,728 B (reused for stats)
  __bf16* wl = (__bf16*)wl4;
  int tid = threadIdx.x;
  int img0 = blockIdx.x * 2;
  {
    const uint32_t* src = s2T + (size_t)img0 * 162;
    for (int i = tid; i < 324; i += 256) sp[i] = src[i];
  }
  int wave = tid >> 6, lane = tid & 63;
  int img_local = wave >> 1, nh = wave & 1;
  int l15 = lane & 15, quad = lane >> 4;
  int qsh = quad * 8;
  int base[4];
  #pragma unroll
  for (int mt = 0; mt < 4; mt++) {
    int px = mt * 16 + l15;
    if (px > 48) px = 48;
    int oy = px / 7, ox = px - oy * 7;
    base[mt] = img_local * 162 + (oy * 9 + ox) * 2;
  }
  f32x4 acc[4][2];
  #pragma unroll
  for (int mt = 0; mt < 4; mt++)
    #pragma unroll
    for (int nt = 0; nt < 2; nt++) acc[mt][nt] = (f32x4){0.f, 0.f, 0.f, 0.f};

  #pragma unroll
  for (int kc = 0; kc < 3; kc++) {
    __syncthreads();
    #pragma unroll
    for (int it = 0; it < 18; it++) {               // async 16B/lane global->LDS
      const __bf16* s = wf + (((it / 6) * 18 + kc * 6 + (it % 6)) << 11) + tid * 8;
      gld_lds16(s, wl + (it << 11) + tid * 8);
    }
    __syncthreads();
    #pragma unroll
    for (int ksl = 0; ksl < 6; ksl++) {
      int kstep = kc * 6 + ksl;
      int pos = kstep >> 1, cihalf = kstep & 1;
      int ky = pos / 3, kx = pos % 3;
      short8 a[4];
      #pragma unroll
      for (int mt = 0; mt < 4; mt++) {
        uint32_t word = sp[base[mt] + (ky * 9 + kx) * 2 + cihalf];
        uint32_t byt = (word >> qsh) & 255u;
        union { uint32_t u[4]; short8 v; } A;
        A.u[0] = ((byt & 1u)  ? 0x3F80u : 0u) | ((byt & 2u)   ? 0x3F800000u : 0u);
        A.u[1] = ((byt & 4u)  ? 0x3F80u : 0u) | ((byt & 8u)   ? 0x3F800000u : 0u);
        A.u[2] = ((byt & 16u) ? 0x3F80u : 0u) | ((byt & 32u)  ? 0x3F800000u : 0u);
        A.u[3] = ((byt & 64u) ? 0x3F80u : 0u) | ((byt & 128u) ? 0x3F800000u : 0u);
        a[mt] = A.v;
      }
      #pragma unroll
      for (int term = 0; term < 3; term++) {
        int fb = ((term * 6 + ksl) << 11) + (quad << 9);
        #pragma unroll
        for (int nt = 0; nt < 2; nt++) {
          short8 b = *(const short8*)(wl + fb + ((((nh << 1) | nt) << 4) + l15) * 8);
          #pragma unroll
          for (int mt = 0; mt < 4; mt++)
            acc[mt][nt] = __builtin_amdgcn_mfma_f32_16x16x32_bf16(a[mt], b, acc[mt][nt], 0, 0, 0);
        }
      }
    }
  }
  float sl[2], sl2[2];
  #pragma unroll
  for (int nt = 0; nt < 2; nt++) {
    sl[nt] = 0.f; sl2[nt] = 0.f;
    int oc = nh * 32 + nt * 16 + l15;
    float bv = bias[oc];
    float* op = out + ((size_t)(img0 + img_local) * 64 + oc) * 49;
    #pragma unroll
    for (int mt = 0; mt < 4; mt++) {
      int pxr = mt * 16 + quad * 4;
      #pragma unroll
      for (int r = 0; r < 4; r++) {
        int px = pxr + r;
        if (px < 49) {
          float v = acc[mt][nt][r] + bv;
          op[px] = v;
          sl[nt] += v; sl2[nt] += v * v;
        }
      }
    }
  }
  __syncthreads();
  float* sred = (float*)wl4;
  #pragma unroll
  for (int nt = 0; nt < 2; nt++) {
    int oc = nh * 32 + nt * 16 + l15;
    int idx = oc * 8 + img_local * 4 + quad;
    sred[idx] = sl[nt];
    sred[512 + idx] = sl2[nt];
  }
  __syncthreads();
  if (tid < 64) {
    float s = 0.f, s2 = 0.f;
    #pragma unroll
    for (int k = 0; k < 8; k++) { s += sred[tid * 8 + k]; s2 += sred[512 + tid * 8 + k]; }
    pout[tid * 512 + blockIdx.x] = s;
    pout[32768 + tid * 512 + blockIdx.x] = s2;
  }
}

// ---------------- fused stage-3 BN+LIF + transpose -> s3T ----------------
__global__ __launch_bounds__(256) void k_lifb3T(const float* __restrict__ h,
                                                const float* __restrict__ mean,
                                                const float* __restrict__ rstd,
                                                const float* __restrict__ g,
                                                const float* __restrict__ bb,
                                                uint32_t* __restrict__ s3T) {
  __shared__ uint32_t sb[224];
  int b = blockIdx.x, half = blockIdx.y;
  int tid = threadIdx.x;
  bool active = tid < 224;
  int row = active ? tid : 0;
  int c = half * 32 + row / 7, py = row % 7;
  float gm = g[c], mm = mean[c], rs = rstd[c], bc = bb[c];
  float v[7];
  #pragma unroll
  for (int j = 0; j < 7; j++) v[j] = 0.f;
  size_t base = ((size_t)b * 64 + c) * 49 + py * 7;
  float cv[7];
  if (active) {
    #pragma unroll
    for (int j = 0; j < 7; j++) cv[j] = h[base + j];
  }
  #pragma unroll 1
  for (int t = 0; t < TT; t++) {
    float nv[7];
    if (active && t < TT - 1) {                     // prefetch t+1 early
      const float* hp = h + (size_t)(t + 1) * E3_ELEMS;
      #pragma unroll
      for (int j = 0; j < 7; j++) nv[j] = hp[base + j];
    }
    if (active) {
      uint32_t w = 0;
      #pragma unroll
      for (int j = 0; j < 7; j++) {
        float xv = gm * (cv[j] - mm) * rs + bc;
        v[j] = v[j] + (xv - v[j]) * 0.5f;
        uint32_t s = (v[j] >= 1.0f);
        w |= s << j;
        if (s) v[j] = 0.f;
      }
      sb[tid] = w;
    }
    BAR_LDS();
    if (tid < 49) {
      int py2 = tid / 7, px = tid - py2 * 7;
      uint32_t wo = 0;
      #pragma unroll
      for (int ci = 0; ci < 32; ci++)
        wo |= ((sb[ci * 7 + py2] >> px) & 1u) << ci;
      s3T[(size_t)(t * 128 + b) * 98 + tid * 2 + half] = wo;
    }
    BAR_LDS();
    if (active && t < TT - 1) {
      #pragma unroll
      for (int j = 0; j < 7; j++) cv[j] = nv[j];
    }
  }
}

// ---------------- fc1 via MFMA ----------------
// v3: M=128 rows/block (grid 8x32) -> wff B-traffic halves (153MB -> 77MB).
// Bit-exact: per-output ks order + 4-wave partial split + ordered reduce unchanged.
__global__ __launch_bounds__(256) void k_fc1m(const uint32_t* __restrict__ s3T,
                                              const __bf16* __restrict__ wf,
                                              float* __restrict__ f1) {
  __shared__ uint32_t aS[12544];                    // 50,176 B; reused as red[] after loop
  int tid = threadIdx.x;
  int row0 = blockIdx.x * 128;
  int oc0  = blockIdx.y * 16;
  {
    const uint32_t* src = s3T + (size_t)row0 * 98;
    for (int i = tid; i < 12544; i += 256) aS[i] = src[i];
  }
  __syncthreads();
  int wave = tid >> 6, lane = tid & 63;
  int l15 = lane & 15, quad = lane >> 4;
  int qsh = quad * 8;
  f32x4 acc[8];
  #pragma unroll
  for (int mt = 0; mt < 8; mt++) acc[mt] = (f32x4){0.f, 0.f, 0.f, 0.f};
  int nIter = (wave < 2) ? 25 : 24;
  #pragma unroll 1
  for (int i = 0; i < nIter; i++) {
    int ks = i * 4 + wave;
    short8 a[8];
    #pragma unroll
    for (int mt = 0; mt < 8; mt++) {
      uint32_t word = aS[(mt * 16 + l15) * 98 + ks];
      uint32_t byt = (word >> qsh) & 255u;
      union { uint32_t u[4]; short8 v; } A;
      A.u[0] = ((byt & 1u)  ? 0x3F80u : 0u) | ((byt & 2u)   ? 0x3F800000u : 0u);
      A.u[1] = ((byt & 4u)  ? 0x3F80u : 0u) | ((byt & 8u)   ? 0x3F800000u : 0u);
      A.u[2] = ((byt & 16u) ? 0x3F80u : 0u) | ((byt & 32u)  ? 0x3F800000u : 0u);
      A.u[3] = ((byt & 64u) ? 0x3F80u : 0u) | ((byt & 128u) ? 0x3F800000u : 0u);
      a[mt] = A.v;
    }
    #pragma unroll
    for (int term = 0; term < 3; term++) {
      size_t fb = ((size_t)((term * 98 + ks) * 4 + quad) * 512 + oc0 + l15) * 8;
      short8 b = *(const short8*)(wf + fb);
      #pragma unroll
      for (int mt = 0; mt < 8; mt++)
        acc[mt] = __builtin_amdgcn_mfma_f32_16x16x32_bf16(a[mt], b, acc[mt], 0, 0, 0);
    }
  }
  __syncthreads();                                  // all aS reads done; reuse as red[]
  float* red = (float*)aS;                          // [4 waves][64 lanes][33] (pad=33)
  #pragma unroll
  for (int mt = 0; mt < 8; mt++)
    #pragma unroll
    for (int r = 0; r < 4; r++)
      red[(wave * 64 + lane) * 33 + mt * 4 + r] = acc[mt][r];
  __syncthreads();
  #pragma unroll
  for (int k = 0; k < 8; k++) {
    int oi = tid + k * 256;                         // 2048 outputs: 128 rows x 16 oc
    int row_l = oi >> 4, oc_l = oi & 15;
    int mt = row_l >> 4, rem = row_l & 15;
    int q2 = rem >> 2, r = rem & 3;
    int ln = q2 * 16 + oc_l;
    float s = red[(0 * 64 + ln) * 33 + mt * 4 + r]; // ordered: ((p0+p1)+p2)+p3
    s += red[(1 * 64 + ln) * 33 + mt * 4 + r];
    s += red[(2 * 64 + ln) * 33 + mt * 4 + r];
    s += red[(3 * 64 + ln) * 33 + mt * 4 + r];
    f1[(size_t)(row0 + row_l) * 512 + oc0 + oc_l] = s;
  }
}

// ---------------- fused: bias + LIF + fco + mean over T ----------
__global__ __launch_bounds__(256) void k_fc1fco(const float* __restrict__ f1,
                                                const float* __restrict__ bias,
                                                const float* __restrict__ w,
                                                const float* __restrict__ fcob,
                                                float* __restrict__ out) {
  int b = blockIdx.x, tid = threadIdx.x;
  int o0 = tid, o1 = tid + 256;
  float bv0 = bias[o0], bv1 = bias[o1];
  float w00 = w[o0], w10 = w[512 + o0];
  float w01 = w[o1], w11 = w[512 + o1];
  float x0[TT], x1[TT];
  #pragma unroll
  for (int t = 0; t < TT; t++) {
    x0[t] = f1[(size_t)(t * 128 + b) * 512 + o0];
    x1[t] = f1[(size_t)(t * 128 + b) * 512 + o1];
  }
  float v0 = 0.f, v1 = 0.f;
  float a0 = 0.f, a1 = 0.f;
  #pragma unroll
  for (int t = 0; t < TT; t++) {
    float s0 = x0[t] + bv0;
    v0 = v0 + (s0 - v0) * 0.5f;
    bool sp0 = (v0 >= 1.0f);
    if (sp0) v0 = 0.f;
    float s1 = x1[t] + bv1;
    v1 = v1 + (s1 - v1) * 0.5f;
    bool sp1 = (v1 >= 1.0f);
    if (sp1) v1 = 0.f;
    if (sp0) { a0 += w00; a1 += w10; }
    if (sp1) { a0 += w01; a1 += w11; }
  }
  __shared__ float l0[256], l1[256];
  l0[tid] = a0; l1[tid] = a1; __syncthreads();
  for (int k = 128; k > 0; k >>= 1) {
    if (tid < k) { l0[tid] += l0[tid + k]; l1[tid] += l1[tid + k]; }
    __syncthreads();
  }
  if (tid == 0) {
    out[b * 2 + 0] = l0[0] * 0.125f + fcob[0];
    out[b * 2 + 1] = l1[0] * 0.125f + fcob[1];
  }
}

extern "C" void kernel_launch(void* const* d_in, const int* in_sizes, int n_in,
                              void* d_out, int out_size, void* d_ws, size_t ws_size,
                              hipStream_t stream) {
  const float* x    = (const float*)d_in[0];
  const float* c1w  = (const float*)d_in[1];
  const float* c1b  = (const float*)d_in[2];
  const float* bn1g = (const float*)d_in[3];
  const float* bn1b = (const float*)d_in[4];
  const float* c2w  = (const float*)d_in[5];
  const float* c2b  = (const float*)d_in[6];
  const float* bn2g = (const float*)d_in[7];
  const float* bn2b = (const float*)d_in[8];
  const float* c3w  = (const float*)d_in[9];
  const float* c3b  = (const float*)d_in[10];
  const float* bn3g = (const float*)d_in[11];
  const float* bn3b = (const float*)d_in[12];
  const float* fc1w = (const float*)d_in[13];
  const float* fc1b = (const float*)d_in[14];
  const float* fcow = (const float*)d_in[15];
  const float* fcob = (const float*)d_in[16];
  float* out = (float*)d_out;

  char* ws = (char*)d_ws;
  float*    h1     = (float*)(ws + 0);                 //  6,553,600
  uint32_t* s1bits = (uint32_t*)(ws + 6553600);        //  2,621,440
  float*    h2     = (float*)(ws + 19660800);          // 21,233,664
  float*    h3     = (float*)(ws + 46202880);          // 12,845,056
  __bf16*   w2f    = (__bf16*)(ws + 60882944);         //    196,608
  __bf16*   w3f    = (__bf16*)(ws + 61079552);         //    221,184
  uint32_t* s2T    = (uint32_t*)(ws + 61300736);       //    663,552
  __bf16*   w1f    = (__bf16*)(ws + 62390272);         //     49,152
  float*    st     = (float*)(ws + 64880640);          //      320 floats
  __bf16*   wff    = (__bf16*)(ws + 67108864);         //  9,633,792
  float*    f1sum  = (float*)(ws + 76742656);          //  2,097,152
  uint32_t* s3T    = (uint32_t*)(ws + 85131264);       //    401,408
  float*    bnpart = (float*)(ws + 85532672);          //    262,144

  prep_all   <<<1040, 256, 0, stream>>>(c1w, c2w, c3w, fc1w, w1f, w2f, w3f, wff);

  k_conv1m   <<<512, 128, 0, stream>>>(x, w1f, c1b, h1, bnpart);
  k_bnfinal2 <<<32, 256, 0, stream>>>(bnpart, 16384, 51200.f, st, st + 32);
  k_lif1b    <<<320, 256, 0, stream>>>(h1, st, st + 32, bn1g, bn1b, s1bits);

  k_conv2m   <<<512, 256, 0, stream>>>(s1bits, w2f, c2b, h2, bnpart);
  k_bnfinal2 <<<64, 256, 0, stream>>>(bnpart, 32768, 82944.f, st + 64, st + 128);
  k_lifb2T   <<<dim3(128, 2), 256, 0, stream>>>(h2, st + 64, st + 128, bn2g, bn2b, s2T);

  k_conv3m   <<<512, 256, 0, stream>>>(s2T, w3f, c3b, h3, bnpart);
  k_bnfinal2 <<<64, 256, 0, stream>>>(bnpart, 32768, 50176.f, st + 192, st + 256);
  k_lifb3T   <<<dim3(128, 2), 256, 0, stream>>>(h3, st + 192, st + 256, bn3g, bn3b, s3T);

  k_fc1m     <<<dim3(8, 32), 256, 0, stream>>>(s3T, wff, f1sum);
  k_fc1fco   <<<128, 256, 0, stream>>>(f1sum, fc1b, fcow, fcob, out);
}